// Round 1
// baseline (96.685 us; speedup 1.0000x reference)
//
#include <hip/hip_runtime.h>
#include <hip/hip_bf16.h>

#define DIM 256
#define HID 64
#define HW 4096          // 64*64
#define KK 2304          // DIM*9
#define LW 72            // LDS row stride (floats): 64 interior + halo + align pad

// ---------------- Kernel 1: global average pool over each (b,c) plane ----------------
__global__ __launch_bounds__(256) void pool_kernel(const float* __restrict__ x,
                                                   float* __restrict__ pooled) {
    int plane = blockIdx.x;                       // b*DIM + c, 8192 planes
    const float4* p = (const float4*)(x + (size_t)plane * HW);
    int tid = threadIdx.x;
    float s = 0.f;
#pragma unroll
    for (int k = 0; k < 4; ++k) {
        float4 v = p[tid + k * 256];
        s += (v.x + v.y) + (v.z + v.w);
    }
    // wave (64-lane) butterfly reduce
#pragma unroll
    for (int off = 32; off > 0; off >>= 1) s += __shfl_down(s, off, 64);
    __shared__ float ws[4];
    int wid = tid >> 6, lane = tid & 63;
    if (lane == 0) ws[wid] = s;
    __syncthreads();
    if (tid == 0) {
        float t = (ws[0] + ws[1]) + (ws[2] + ws[3]);
        pooled[plane] = t * (1.0f / (float)HW);
    }
}

// ---------------- Kernel 2: SE weight generation (1x1 conv -> BN -> sigmoid -> 1x1 conv) ----------------
__global__ __launch_bounds__(256) void gen_kernel(const float* __restrict__ pooled,
                                                  const float* __restrict__ w1,
                                                  const float* __restrict__ gamma,
                                                  const float* __restrict__ beta,
                                                  const float* __restrict__ mean,
                                                  const float* __restrict__ var,
                                                  const float* __restrict__ w2,
                                                  const float* __restrict__ b2,
                                                  float* __restrict__ dyn) {
    int b = blockIdx.x;          // 32 blocks
    int tid = threadIdx.x;       // 256 threads
    __shared__ float sp[DIM];
    __shared__ float sig[HID];
    sp[tid] = pooled[b * DIM + tid];
    __syncthreads();
    if (tid < HID) {
        const float* wr = w1 + tid * DIM;
        float acc = 0.f;
#pragma unroll 8
        for (int c = 0; c < DIM; ++c) acc += sp[c] * wr[c];
        float yb = (acc - mean[tid]) * rsqrtf(var[tid] + 1e-5f) * gamma[tid] + beta[tid];
        sig[tid] = 1.0f / (1.0f + expf(-yb));
    }
    __syncthreads();
    for (int k = tid; k < KK; k += 256) {
        const float* wk = w2 + k * HID;
        float acc = b2[k];
#pragma unroll
        for (int r = 0; r < HID; ++r) acc += sig[r] * wk[r];
        dyn[b * KK + k] = acc;
    }
}

// ---------------- Kernel 3: per-sample depthwise 3x3 conv, one block per (b,c) plane ----------------
__global__ __launch_bounds__(256) void conv_kernel(const float* __restrict__ x,
                                                   const float* __restrict__ dyn,
                                                   const float* __restrict__ bias,
                                                   float* __restrict__ out) {
    int plane = blockIdx.x;                  // b*DIM + c
    int c = plane & (DIM - 1);
    int b = plane >> 8;
    int tid = threadIdx.x;
    const float* xp = x + (size_t)plane * HW;
    float* op = out + (size_t)plane * HW;

    __shared__ float lds[66 * LW];

    // 3x3 weights for this plane (uniform across block)
    const float* wp = dyn + b * KK + c * 9;
    float w[9];
#pragma unroll
    for (int i = 0; i < 9; ++i) w[i] = wp[i];

    // zero the halo: full rows 0 and 65, plus cols 3 and 68 for rows 1..64
    for (int i = tid; i < 272; i += 256) {
        int addr;
        if (i < 72)        addr = i;                         // top row
        else if (i < 144)  addr = 65 * LW + (i - 72);        // bottom row
        else if (i < 208)  addr = (i - 144 + 1) * LW + 3;    // left halo col
        else               addr = (i - 208 + 1) * LW + 68;   // right halo col
        lds[addr] = 0.f;
    }

    // interior: x[gy][gx] -> lds[(gy+1)*LW + 4 + gx], loaded as float4
    const float4* xp4 = (const float4*)xp;
#pragma unroll
    for (int k = 0; k < 4; ++k) {
        int idx = tid + k * 256;             // 0..1023 float4s
        int row = idx >> 4;                  // 16 float4 per row
        int col4 = idx & 15;
        float4 v = xp4[idx];
        *(float4*)&lds[(row + 1) * LW + 4 + col4 * 4] = v;   // 16B-aligned
    }
    __syncthreads();

    float bv = bias[c];
    float4* op4 = (float4*)op;
#pragma unroll
    for (int g = 0; g < 4; ++g) {
        int q = tid + g * 256;               // float4 output index
        int row = q >> 4;
        int col0 = (q & 15) * 4;
        float s0 = bv, s1 = bv, s2 = bv, s3 = bv;
#pragma unroll
        for (int dy = 0; dy < 3; ++dy) {
            const float* r = &lds[(row + dy) * LW + 3 + col0];   // r[0] = (row+dy-1, col0-1)
            float a0 = r[0], a1 = r[1], a2 = r[2], a3 = r[3], a4 = r[4], a5 = r[5];
            float w0 = w[dy * 3 + 0], w1v = w[dy * 3 + 1], w2v = w[dy * 3 + 2];
            s0 += w0 * a0 + w1v * a1 + w2v * a2;
            s1 += w0 * a1 + w1v * a2 + w2v * a3;
            s2 += w0 * a2 + w1v * a3 + w2v * a4;
            s3 += w0 * a3 + w1v * a4 + w2v * a5;
        }
        float4 o;
        o.x = s0; o.y = s1; o.z = s2; o.w = s3;
        op4[q] = o;
    }
}

extern "C" void kernel_launch(void* const* d_in, const int* in_sizes, int n_in,
                              void* d_out, int out_size, void* d_ws, size_t ws_size,
                              hipStream_t stream) {
    const float* x     = (const float*)d_in[0];
    const float* w1    = (const float*)d_in[1];
    const float* gamma = (const float*)d_in[2];
    const float* beta  = (const float*)d_in[3];
    const float* mean  = (const float*)d_in[4];
    const float* var   = (const float*)d_in[5];
    const float* w2    = (const float*)d_in[6];
    const float* b2    = (const float*)d_in[7];
    const float* bias  = (const float*)d_in[8];
    float* out = (float*)d_out;

    float* pooled = (float*)d_ws;            // 8192 floats
    float* dyn = pooled + 8192;              // 32*2304 = 73728 floats

    pool_kernel<<<8192, 256, 0, stream>>>(x, pooled);
    gen_kernel<<<32, 256, 0, stream>>>(pooled, w1, gamma, beta, mean, var, w2, b2, dyn);
    conv_kernel<<<8192, 256, 0, stream>>>(x, dyn, bias, out);
}